// Round 6
// baseline (223.984 us; speedup 1.0000x reference)
//
#include <hip/hip_runtime.h>
#include <cstddef>
#include <cstdint>

typedef float f32x4 __attribute__((ext_vector_type(4)));
typedef short bf16x8 __attribute__((ext_vector_type(8)));

__device__ __forceinline__ float fast_exp2(float x) { return __builtin_amdgcn_exp2f(x); }
__device__ __forceinline__ float fast_log2(float x) { return __builtin_amdgcn_logf(x); }

__device__ __forceinline__ short bf16rne(float x) {
  uint32_t u = __float_as_uint(x);
  u += 0x7fffu + ((u >> 16) & 1u);
  return (short)(u >> 16);
}

namespace {
constexpr int Bc = 256, Tc = 1024, Kc = 128;
constexpr int NC = 96;          // time chunks -> 1536 one-wave blocks = 6 waves/CU
constexpr int WARM = 12;        // Birkhoff warmup (R2/R5-proven, absmax 0.0)
constexpr int MEAS = 1023 - WARM;  // 1011; s_c = floor(1011*c/96), L in {10,11}
constexpr float L2E = 1.4426950408889634f;
constexpr float LN2 = 0.6931471805599453f;
constexpr int WS_ET2 = NC * Bc;    // float offset of permuted exp(trans) (16384 ushort)
// ws: contrib[96][256] floats (96KB) + ET2p bf16[128][128] (32KB) = 128KB.
}

// R5 post-mortem: per-block-step cost is pinned at ~1550 CU-cycles regardless of
// blocks/CU (R1 646ns@1 -> R5 ~1.9us-equiv@6): the 4-wave bar_lds exchange is a
// per-CU throughput tax ~7x the actual issue work (~200 cyc). Fix: barrier-free
// single-wave chains via a POSITION PERMUTATION folded into A.
//
// MFMA 16x16x32 layouts (proven by the running kernel): B-slot (lane q, short j)
// holds k_loc = 8q+j; C (lane q, reg r) holds row 4q+r; batch col = lane&15 for
// both. Define storage permutation phi(tt,q,j): position (32tt+8q+j) stores true
// tag tau = 32tt + 16*(j>>2) + 4q + (j&3). Then the C output registers ARE the
// next B operand verbatim: Bf[tt] = [bf16(P[2tt].xyzw), bf16(P[2tt+1].xyzw)] —
// zero cross-lane motion. Compensation: A-frag element (nt,tt,lane q,slot jj)
// must hold exp(trans)[tau(tt,8q+jj)][16nt+b] — precomputed by crf_prep as
// ET2p[m][c] = bf16(2^(trans[tau(c)][m]*L2E)), tau(c) a bit-permute, so A-frags
// are contiguous 16B loads. Emissions/measure/rescale all index TRUE tags
// (C-layout: tag = 16nt+4q+r), unchanged from the proven engine.
//
// Per wave (one (batch-group, chunk)): A 128 VGPR + er 32 + Bf 16 + P 32 ~= 250.
// Per-step: 32 MFMA + 32 fused exp2(e*L2E + sf) + 32 mul + 32 bf16 packs + one
// __shfl broadcast of tag0 for the lag-1 pow2 rescale (sf = 127-ex folded into
// the exp2 argument; exact-pow2 scaling error ~1ulp/step << bf16 noise).
// Telescope (R2-proven): chunk c warm-starts (ones) at s_c, 12 warmup steps,
// Amid at s_c+12, L_c in {10,11} measured steps, Aend at s_{c+1}+12; chunk 0
// exact-start, chunk 95 end-weighted. logZ = LN2*[Aend^0 + sum(Aend-Amid)].
__global__ __launch_bounds__(128, 1) void crf_prep(
    const float* __restrict__ trans, float* __restrict__ ws)
{
  unsigned short* et = reinterpret_cast<unsigned short*>(ws + WS_ET2);
  const int m = (int)blockIdx.x;   // output tag row 0..127
  const int c = (int)threadIdx.x;  // permuted k position 0..127
  // tau: bits 0,1,5,6 identity; tau bit4 <- c bit2; tau bits2,3 <- c bits3,4.
  const int tau = (c & 0x63) | ((c & 4) << 2) | ((c & 0x18) >> 1);
  et[(size_t)m * Kc + c] =
      (unsigned short)bf16rne(fast_exp2(trans[(size_t)tau * Kc + m] * L2E));
}

__global__ __launch_bounds__(64) void crf_chunk_kernel(
    const float* __restrict__ hs,
    const float* __restrict__ start_t,
    const float* __restrict__ end_t,
    float* __restrict__ ws)
{
  const int lane = (int)threadIdx.x;
  const int b = lane & 15;               // batch row within group
  const int q = lane >> 4;               // quad group 0..3
  const int rb = (int)blockIdx.x & 15;   // batch group
  const int ck = (int)blockIdx.x >> 4;   // time chunk 0..95
  const int brow = rb * 16 + b;
  const int s0 = (MEAS * ck) / NC;
  const int L  = (MEAS * (ck + 1)) / NC - s0;   // 10 or 11
  const int NSTEPS = WARM + L;                  // 22 or 23
  const float* __restrict__ eb = hs + (size_t)brow * Tc * Kc + (size_t)s0 * Kc;
  const unsigned short* __restrict__ et =
      reinterpret_cast<const unsigned short*>(ws + WS_ET2);

  // A-frags: Ap[nt][tt] = ET2p row (16nt+b), cols 32tt+8q..+7 — one 16B load each.
  bf16x8 Ap[8][4];
#pragma unroll
  for (int nt = 0; nt < 8; ++nt)
#pragma unroll
    for (int tt = 0; tt < 4; ++tt)
      Ap[nt][tt] = *(const bf16x8*)&et[(size_t)(16 * nt + b) * Kc + 32 * tt + 8 * q];

  // Emission buffer (depth-1): er[nt] = e[row][16nt+4q..+3] in TRUE tag order.
  f32x4 er[8];
#pragma unroll
  for (int nt = 0; nt < 8; ++nt)
    er[nt] = *(const f32x4*)&eb[(size_t)Kc + 16 * nt + 4 * q];   // row 1

  // Bf init in phi-storage. ck==0 exact: pos (tt,q,j) = 2^((start+e0)[tau]*L2E),
  // tau runs {32tt+4q+0..3} for j<4 and +16 for j>=4. ck>0: all-ones.
  bf16x8 Bf[4];
  if (ck == 0) {
#pragma unroll
    for (int tt = 0; tt < 4; ++tt) {
      f32x4 sv0 = *(const f32x4*)&start_t[32 * tt + 4 * q];
      f32x4 sv1 = *(const f32x4*)&start_t[32 * tt + 4 * q + 16];
      f32x4 e0v = *(const f32x4*)&eb[32 * tt + 4 * q];
      f32x4 e1v = *(const f32x4*)&eb[32 * tt + 4 * q + 16];
      bf16x8 v;
      v[0] = bf16rne(fast_exp2((sv0.x + e0v.x) * L2E));
      v[1] = bf16rne(fast_exp2((sv0.y + e0v.y) * L2E));
      v[2] = bf16rne(fast_exp2((sv0.z + e0v.z) * L2E));
      v[3] = bf16rne(fast_exp2((sv0.w + e0v.w) * L2E));
      v[4] = bf16rne(fast_exp2((sv1.x + e1v.x) * L2E));
      v[5] = bf16rne(fast_exp2((sv1.y + e1v.y) * L2E));
      v[6] = bf16rne(fast_exp2((sv1.z + e1v.z) * L2E));
      v[7] = bf16rne(fast_exp2((sv1.w + e1v.w) * L2E));
      Bf[tt] = v;
    }
  } else {
    const short one = (short)0x3F80;
#pragma unroll
    for (int tt = 0; tt < 4; ++tt) {
      bf16x8 v;
#pragma unroll
      for (int j = 0; j < 8; ++j) v[j] = one;
      Bf[tt] = v;
    }
  }

  float sf = 0.f;    // log2 of carried scale (lag-1, exact integer)
  int curE0 = 0;
  int Mi = 0;
  f32x4 P[8];        // post-emission state, TRUE tag (16nt+4q+r), f32

// One step, literal T. MFMA+emission fused per nt (Cv transient); refill after
// er consumed; pack = componentwise bf16 of P pairs (phi makes it identity).
#define STEP(T) do {                                                            \
    const f32x4 z4 = {0.f, 0.f, 0.f, 0.f};                                      \
    Mi += curE0;                                                                \
    float c00src = 0.f;                                                         \
    _Pragma("unroll")                                                           \
    for (int nt = 0; nt < 8; ++nt) {                                            \
      f32x4 c01 = __builtin_amdgcn_mfma_f32_16x16x32_bf16(Ap[nt][1], Bf[1],     \
          __builtin_amdgcn_mfma_f32_16x16x32_bf16(Ap[nt][0], Bf[0], z4, 0, 0, 0), \
          0, 0, 0);                                                             \
      f32x4 c23 = __builtin_amdgcn_mfma_f32_16x16x32_bf16(Ap[nt][3], Bf[3],     \
          __builtin_amdgcn_mfma_f32_16x16x32_bf16(Ap[nt][2], Bf[2], z4, 0, 0, 0), \
          0, 0, 0);                                                             \
      f32x4 cv = c01 + c23;                                                     \
      if (nt == 0) c00src = cv.x;                                               \
      f32x4 e = er[nt];                                                         \
      f32x4 p;                                                                  \
      p.x = cv.x * fast_exp2(__builtin_fmaf(e.x, L2E, sf));                     \
      p.y = cv.y * fast_exp2(__builtin_fmaf(e.y, L2E, sf));                     \
      p.z = cv.z * fast_exp2(__builtin_fmaf(e.z, L2E, sf));                     \
      p.w = cv.w * fast_exp2(__builtin_fmaf(e.w, L2E, sf));                     \
      P[nt] = p;                                                                \
    }                                                                           \
    {                                                                           \
      int rn = (T) + 1; if (rn > NSTEPS) rn = NSTEPS;                           \
      _Pragma("unroll")                                                         \
      for (int nt = 0; nt < 8; ++nt)                                            \
        er[nt] = *(const f32x4*)&eb[(size_t)rn * Kc + 16 * nt + 4 * q];         \
    }                                                                           \
    float c00 = __shfl(c00src, b, 64);  /* tag0 value for batch b (lane q=0) */ \
    _Pragma("unroll")                                                           \
    for (int tt = 0; tt < 4; ++tt) {                                            \
      bf16x8 v;                                                                 \
      v[0] = bf16rne(P[2 * tt].x);     v[1] = bf16rne(P[2 * tt].y);             \
      v[2] = bf16rne(P[2 * tt].z);     v[3] = bf16rne(P[2 * tt].w);             \
      v[4] = bf16rne(P[2 * tt + 1].x); v[5] = bf16rne(P[2 * tt + 1].y);         \
      v[6] = bf16rne(P[2 * tt + 1].z); v[7] = bf16rne(P[2 * tt + 1].w);         \
      Bf[tt] = v;                                                               \
    }                                                                           \
    {                                                                           \
      uint32_t ex = (__float_as_uint(c00) >> 23) & 0xffu;                       \
      curE0 = (int)ex - 127;                                                    \
      sf = (float)(127 - (int)ex);                                              \
    }                                                                           \
  } while (0)

// A = Mi + log2(sum_tags P) per batch row; valid on lanes with q==0 (lane<16).
#define MEASURE(DST, WEIGHTED) do {                                             \
    float part = 0.f;                                                           \
    if (WEIGHTED) {                                                             \
      _Pragma("unroll")                                                         \
      for (int nt = 0; nt < 8; ++nt) {                                          \
        f32x4 ev = *(const f32x4*)&end_t[16 * nt + 4 * q];                      \
        part += P[nt].x * fast_exp2(ev.x * L2E) + P[nt].y * fast_exp2(ev.y * L2E) \
              + P[nt].z * fast_exp2(ev.z * L2E) + P[nt].w * fast_exp2(ev.w * L2E); \
      }                                                                         \
    } else {                                                                    \
      _Pragma("unroll")                                                         \
      for (int nt = 0; nt < 8; ++nt)                                            \
        part += P[nt].x + P[nt].y + P[nt].z + P[nt].w;                          \
    }                                                                           \
    part += __shfl_xor(part, 16);                                               \
    part += __shfl_xor(part, 32);                                               \
    DST = (float)Mi + fast_log2(part);                                          \
  } while (0)

  // Phase 1: local steps 1..12 (warmup; measured for ck==0), then Amid.
  STEP(1);  STEP(2);  STEP(3);  STEP(4);
  STEP(5);  STEP(6);  STEP(7);  STEP(8);
  STEP(9);  STEP(10); STEP(11); STEP(12);
  float Amid; MEASURE(Amid, false);

  // Phase 2: local steps 13..12+L (L in {10,11}).
  STEP(13); STEP(14); STEP(15); STEP(16);
  STEP(17); STEP(18); STEP(19); STEP(20);
  STEP(21); STEP(22);
  if (L == 11) { STEP(23); }
  float Aend; MEASURE(Aend, (ck == NC - 1));

#undef STEP
#undef MEASURE

  if (lane < 16)
    ws[(size_t)ck * Bc + brow] = Aend - (ck ? Amid : 0.f);
}

// logZ_b = ln2 * sum_c contrib[c][b]
__global__ __launch_bounds__(256, 1) void crf_combine(
    const float* __restrict__ ws, float* __restrict__ out)
{
  const int b = (int)threadIdx.x;
  float s = 0.f;
#pragma unroll
  for (int cc = 0; cc < NC; ++cc) s += ws[(size_t)cc * Bc + b];
  out[b] = s * LN2;
}

extern "C" void kernel_launch(void* const* d_in, const int* in_sizes, int n_in,
                              void* d_out, int out_size, void* d_ws, size_t ws_size,
                              hipStream_t stream) {
  const float* hs    = (const float*)d_in[0];
  const float* trans = (const float*)d_in[1];
  const float* st    = (const float*)d_in[2];
  const float* en    = (const float*)d_in[3];
  float* ws = (float*)d_ws;   // needs 24576 + 8192 floats = 128 KB
  crf_prep<<<dim3(Kc), dim3(Kc), 0, stream>>>(trans, ws);
  crf_chunk_kernel<<<dim3(NC * 16), dim3(64), 0, stream>>>(hs, st, en, ws);
  crf_combine<<<dim3(1), dim3(Bc), 0, stream>>>(ws, (float*)d_out);
}